// Round 3
// baseline (2693.159 us; speedup 1.0000x reference)
//
#include <hip/hip_runtime.h>
#include <hip/hip_bf16.h>
#include <type_traits>
#include <utility>

typedef unsigned short u16;
typedef unsigned int u32;

#define B_ 2
#define T_ 2048
#define C_ 2048
#define H_ 16
#define D_ 128
#define LDQKV 6144  // row stride of qkv [B*T, 3C]

typedef float float4v __attribute__((ext_vector_type(4)));
typedef short short8 __attribute__((ext_vector_type(8)));

__device__ inline u16 f2bf(float f) {
  u32 u = __builtin_bit_cast(u32, f);
  u32 r = u + 0x7fffu + ((u >> 16) & 1u);  // RNE
  return (u16)(r >> 16);
}
__device__ inline float bfbits2f(u16 b) {
  return __builtin_bit_cast(float, (u32)b << 16);
}
__device__ inline void unpack2(u32 u, float& lo, float& hi) {
  lo = __builtin_bit_cast(float, u << 16);
  hi = __builtin_bit_cast(float, u & 0xffff0000u);
}

#if defined(__HIP_DEVICE_COMPILE__)
typedef __bf16 bf16x8 __attribute__((ext_vector_type(8)));

// ROCm versions differ on whether the gfx950 bf16 MFMA builtin takes short8 or
// __bf16x8. SFINAE-detect and bit_cast if needed so either signature compiles.
template <typename V, typename = void>
struct mfma_takes_short : std::false_type {};
template <typename V>
struct mfma_takes_short<V, std::void_t<decltype(__builtin_amdgcn_mfma_f32_16x16x32_bf16(
    std::declval<V>(), std::declval<V>(), std::declval<float4v>(), 0, 0, 0))>>
    : std::true_type {};

template <typename SV>
__device__ inline float4v mfma_bf16(SV a, SV b, float4v c) {
  if constexpr (mfma_takes_short<SV>::value) {
    return __builtin_amdgcn_mfma_f32_16x16x32_bf16(a, b, c, 0, 0, 0);
  } else {
    return __builtin_amdgcn_mfma_f32_16x16x32_bf16(
        __builtin_bit_cast(bf16x8, a), __builtin_bit_cast(bf16x8, b), c, 0, 0, 0);
  }
}
#endif

// C[M,N] = A[M,K] @ B[K,N], fp32 accum. A/B fp32 or bf16 per template (fp32 is
// converted RNE->bf16 while staging into LDS); C stored bf16 or fp32 per CF32.
// 64x64 tile, BK=32, 256 threads (4 waves), wave w -> 16-row output stripe.
template <bool AF32, bool BF32, bool CF32>
__global__ __launch_bounds__(256) void gemm_mixed(const void* __restrict__ Ap,
                                                  const void* __restrict__ Bp,
                                                  void* __restrict__ Cp,
                                                  int M, int N, int K,
                                                  int lda, int ldb, int ldc) {
#if defined(__HIP_DEVICE_COMPILE__)
  __shared__ u16 As[64][40];  // [m][k], +8 pad
  __shared__ u16 Bs[64][40];  // [n][k] (transposed at stage), +8 pad
  const int tid = threadIdx.x;
  const int lane = tid & 63;
  const int w = tid >> 6;
  const int m0 = blockIdx.y * 64;
  const int n0 = blockIdx.x * 64;
  const int arow = tid >> 2, acol = (tid & 3) * 8;
  const int brow = tid >> 3, bcol = (tid & 7) * 8;
  const int ml = lane & 15, qd = lane >> 4;
  float4v acc[4] = {};
  for (int kk = 0; kk < K; kk += 32) {
    __syncthreads();
    // ---- stage A tile (rows m0..m0+63, k kk..kk+31) ----
    if constexpr (AF32) {
      const float* A = (const float*)Ap;
      const float* src = A + (size_t)(m0 + arow) * lda + (kk + acol);
      float4 f0 = *(const float4*)src;
      float4 f1 = *(const float4*)(src + 4);
      alignas(16) u16 tmp[8] = {f2bf(f0.x), f2bf(f0.y), f2bf(f0.z), f2bf(f0.w),
                                f2bf(f1.x), f2bf(f1.y), f2bf(f1.z), f2bf(f1.w)};
      *(uint4*)(&As[arow][acol]) = *(const uint4*)tmp;
    } else {
      const u16* A = (const u16*)Ap;
      uint4 av = *(const uint4*)(A + (size_t)(m0 + arow) * lda + (kk + acol));
      *(uint4*)(&As[arow][acol]) = av;
    }
    // ---- stage B tile transposed: Bs[n][k] ----
    if constexpr (BF32) {
      const float* Bm = (const float*)Bp;
      const float* src = Bm + (size_t)(kk + brow) * ldb + (n0 + bcol);
      float4 f0 = *(const float4*)src;
      float4 f1 = *(const float4*)(src + 4);
      float fv[8] = {f0.x, f0.y, f0.z, f0.w, f1.x, f1.y, f1.z, f1.w};
#pragma unroll
      for (int i = 0; i < 8; ++i) Bs[bcol + i][brow] = f2bf(fv[i]);
    } else {
      const u16* Bm = (const u16*)Bp;
      uint4 bv = *(const uint4*)(Bm + (size_t)(kk + brow) * ldb + (n0 + bcol));
      const u16* bsp = (const u16*)&bv;
#pragma unroll
      for (int i = 0; i < 8; ++i) Bs[bcol + i][brow] = bsp[i];
    }
    __syncthreads();
    // A-frag: lane holds A[m=lane&15][k=quad*8+j]
    short8 af = *(const short8*)(&As[w * 16 + ml][qd * 8]);
#pragma unroll
    for (int nt = 0; nt < 4; ++nt) {
      // B-frag: lane holds B[k=quad*8+j][n=lane&15] (rows of Bs are n)
      short8 bf = *(const short8*)(&Bs[nt * 16 + ml][qd * 8]);
      acc[nt] = mfma_bf16(af, bf, acc[nt]);
    }
  }
  // C/D: col=lane&15, row=quad*4+reg
#pragma unroll
  for (int nt = 0; nt < 4; ++nt) {
#pragma unroll
    for (int r = 0; r < 4; ++r) {
      int row = m0 + w * 16 + qd * 4 + r;
      int col = n0 + nt * 16 + ml;
      if constexpr (CF32) {
        ((float*)Cp)[(size_t)row * ldc + col] = acc[nt][r];
      } else {
        ((u16*)Cp)[(size_t)row * ldc + col] = f2bf(acc[nt][r]);
      }
    }
  }
#endif
}

// In-place RoPE on qkv [B,T,3C] bf16: rotates q (cols 0..C) and k (cols C..2C).
// One thread per (b,t,h,d<64).
__global__ __launch_bounds__(256) void rope_inplace(u16* __restrict__ qkv) {
  int idx = blockIdx.x * 256 + threadIdx.x;  // B*T*H*64 threads
  int d = idx & 63;
  int h = (idx >> 6) & 15;
  int t = (idx >> 10) & 2047;
  int b = idx >> 21;
  size_t row = (size_t)(b * T_ + t) * LDQKV;
  u16* qp = qkv + row + h * 128;
  u16* kp = qkv + row + C_ + h * 128;
  float q1 = bfbits2f(qp[d]);
  float q2 = bfbits2f(qp[d + 64]);
  float k1 = bfbits2f(kp[d]);
  float k2 = bfbits2f(kp[d + 64]);
  // inv_freq = 10000^(-d/64) = 2^(-d * log2(10000)/64)
  float invf = exp2f((float)d * -0.20762050593046012f);
  float fr = (float)t * invf;
  float sn, cs;
  sincosf(fr, &sn, &cs);
  qp[d] = f2bf(q1 * cs - q2 * sn);
  qp[d + 64] = f2bf(q2 * cs + q1 * sn);
  kp[d] = f2bf(k1 * cs - k2 * sn);
  kp[d + 64] = f2bf(k2 * cs + k1 * sn);
}

// Flash-style causal attention reading Q/K/V strided from qkv [B,T,3C] bf16.
// Y (= O, pre-out-proj) is written back into the Q columns of qkv (safe: each
// block reads Q only for its own (tile,head) slice before writing it, and
// other blocks never touch those (row,col) ranges).
// Block = (q-tile of 64 rows, one (b,h)). 4 waves; wave w owns q rows w*16..+15.
__global__ __launch_bounds__(256) void attn_fwd(u16* __restrict__ qkv) {
  __shared__ u16 qs[64][128];
  __shared__ u16 ks[64][128];  // row j rotated by j*8 elems (bank-conflict fix)
  __shared__ u16 vs[64][128];
  __shared__ float ps[4][16][64];  // per-wave softmax weights
  const int tid = threadIdx.x;
  const int lane = tid & 63;
  const int w = tid >> 6;
  const int qt = blockIdx.x;
  const int bh = blockIdx.y;
  const int b = bh >> 4, h = bh & 15;
  const int hc = h * 128;
  const int srow = tid >> 2;
  const int scol = (tid & 3) * 32;
  {
    size_t row = (size_t)(b * T_ + qt * 64 + srow) * LDQKV + hc;
    const uint4* src = (const uint4*)(qkv + row + scol);
#pragma unroll
    for (int i = 0; i < 4; ++i) *(uint4*)&qs[srow][scol + i * 8] = src[i];
  }
  float m_i[16], l_i[16], ox[16], oy[16];
#pragma unroll
  for (int r = 0; r < 16; ++r) { m_i[r] = -1.0e30f; l_i[r] = 0.f; ox[r] = 0.f; oy[r] = 0.f; }
  const float scale = 0.08838834764831845f;  // 1/sqrt(128)

  for (int c = 0; c <= qt; ++c) {
    __syncthreads();
    {
      size_t row = (size_t)(b * T_ + c * 64 + srow) * LDQKV + hc;
      const uint4* ksrc = (const uint4*)(qkv + row + C_ + scol);
      const uint4* vsrc = (const uint4*)(qkv + row + 2 * C_ + scol);
#pragma unroll
      for (int i = 0; i < 4; ++i) {
        int kc = (scol + i * 8 + srow * 8) & 127;  // swizzle k rows
        *(uint4*)&ks[srow][kc] = ksrc[i];
        *(uint4*)&vs[srow][scol + i * 8] = vsrc[i];
      }
    }
    __syncthreads();
    // Phase A: lane = key j in chunk; scores for 16 q rows
    float sc[16];
#pragma unroll
    for (int r = 0; r < 16; ++r) sc[r] = 0.f;
#pragma unroll 2
    for (int d8 = 0; d8 < 16; ++d8) {
      int kc = ((d8 + lane) & 15) * 8;  // unswizzle
      uint4 kv = *(const uint4*)&ks[lane][kc];
      const u32* kp = (const u32*)&kv;
      float kf[8];
#pragma unroll
      for (int i = 0; i < 4; ++i) unpack2(kp[i], kf[2 * i], kf[2 * i + 1]);
#pragma unroll
      for (int r = 0; r < 16; ++r) {
        uint4 qv = *(const uint4*)&qs[w * 16 + r][d8 * 8];  // broadcast
        const u32* qp = (const u32*)&qv;
        float s0 = sc[r];
#pragma unroll
        for (int i = 0; i < 4; ++i) {
          float q0, q1;
          unpack2(qp[i], q0, q1);
          s0 += q0 * kf[2 * i] + q1 * kf[2 * i + 1];
        }
        sc[r] = s0;
      }
    }
    // Online softmax per row
    const bool diag = (c == qt);
#pragma unroll
    for (int r = 0; r < 16; ++r) {
      float s0 = sc[r] * scale;
      if (diag && lane > (w * 16 + r)) s0 = -1.0e30f;  // causal mask
      float mx = s0;
#pragma unroll
      for (int off = 32; off > 0; off >>= 1) mx = fmaxf(mx, __shfl_xor(mx, off, 64));
      float mnew = fmaxf(m_i[r], mx);
      float p = __expf(s0 - mnew);
      float alpha = __expf(m_i[r] - mnew);
      float sm = p;
#pragma unroll
      for (int off = 32; off > 0; off >>= 1) sm += __shfl_xor(sm, off, 64);
      l_i[r] = l_i[r] * alpha + sm;
      m_i[r] = mnew;
      ox[r] *= alpha;
      oy[r] *= alpha;
      ps[w][r][lane] = p;
    }
    __syncthreads();
    // Phase B: lane = d-pair (d0=2*lane); o += P @ V
    const int d0 = lane * 2;
#pragma unroll 4
    for (int j4 = 0; j4 < 16; ++j4) {
      float vx[4], vy[4];
#pragma unroll
      for (int jj = 0; jj < 4; ++jj) {
        u32 u = *(const u32*)&vs[j4 * 4 + jj][d0];
        unpack2(u, vx[jj], vy[jj]);
      }
#pragma unroll
      for (int r = 0; r < 16; ++r) {
        float4v p4 = *(const float4v*)&ps[w][r][j4 * 4];  // broadcast
        ox[r] += p4[0] * vx[0] + p4[1] * vx[1] + p4[2] * vx[2] + p4[3] * vx[3];
        oy[r] += p4[0] * vy[0] + p4[1] * vy[1] + p4[2] * vy[2] + p4[3] * vy[3];
      }
    }
  }
  const int d0 = lane * 2;
#pragma unroll
  for (int r = 0; r < 16; ++r) {
    int t = qt * 64 + w * 16 + r;
    float inv = 1.0f / l_i[r];
    u32 pack = (u32)f2bf(ox[r] * inv) | ((u32)f2bf(oy[r] * inv) << 16);
    // write Y into the (already-consumed) Q columns of qkv
    *(u32*)&qkv[(size_t)(b * T_ + t) * LDQKV + hc + d0] = pack;
  }
}

extern "C" void kernel_launch(void* const* d_in, const int* in_sizes, int n_in,
                              void* d_out, int out_size, void* d_ws, size_t ws_size,
                              hipStream_t stream) {
  const float* x = (const float*)d_in[0];     // [B,T,C] fp32
  const float* wqkv = (const float*)d_in[1];  // [C,3C] fp32
  const float* wout = (const float*)d_in[2];  // [C,C] fp32
  float* out = (float*)d_out;                 // [B,T,C] fp32 (reference output dtype)
  // ws: qkv [B*T, 3C] bf16 = 48 MB. Q cols are reused as attention-output Y.
  u16* qkv = (u16*)d_ws;

  // 1) qkv = x @ w_qkv  (fp32 inputs cast bf16 at staging; C stored bf16)
  gemm_mixed<true, true, false><<<dim3(96, 64), dim3(256), 0, stream>>>(
      x, wqkv, qkv, 4096, 6144, 2048, 2048, 6144, 6144);
  // 2) RoPE q,k in place
  rope_inplace<<<dim3(16384), dim3(256), 0, stream>>>(qkv);
  // 3) causal flash attention; Y -> Q columns of qkv
  attn_fwd<<<dim3(32, 32), dim3(256), 0, stream>>>(qkv);
  // 4) out = Y @ w_out  (A = qkv cols 0..2047 with lda=6144; C stored fp32)
  gemm_mixed<false, true, true><<<dim3(32, 64), dim3(256), 0, stream>>>(
      qkv, wout, out, 4096, 2048, 2048, 6144, 2048, 2048);
}

// Round 4
// 949.455 us; speedup vs baseline: 2.8365x; 2.8365x over previous
//
#include <hip/hip_runtime.h>
#include <hip/hip_bf16.h>
#include <type_traits>
#include <utility>

typedef unsigned short u16;
typedef unsigned int u32;

#define B_ 2
#define T_ 2048
#define C_ 2048
#define H_ 16
#define D_ 128
#define LDQKV 6144  // row stride of qkv [B*T, 3C]

typedef float float4v __attribute__((ext_vector_type(4)));
typedef short short8 __attribute__((ext_vector_type(8)));

__device__ inline u16 f2bf(float f) {
  u32 u = __builtin_bit_cast(u32, f);
  u32 r = u + 0x7fffu + ((u >> 16) & 1u);  // RNE
  return (u16)(r >> 16);
}
__device__ inline float bfbits2f(u16 b) {
  return __builtin_bit_cast(float, (u32)b << 16);
}

#if defined(__HIP_DEVICE_COMPILE__)
typedef __bf16 bf16x8 __attribute__((ext_vector_type(8)));

template <typename V, typename = void>
struct mfma_takes_short : std::false_type {};
template <typename V>
struct mfma_takes_short<V, std::void_t<decltype(__builtin_amdgcn_mfma_f32_16x16x32_bf16(
    std::declval<V>(), std::declval<V>(), std::declval<float4v>(), 0, 0, 0))>>
    : std::true_type {};

template <typename SV>
__device__ inline float4v mfma_bf16(SV a, SV b, float4v c) {
  if constexpr (mfma_takes_short<SV>::value) {
    return __builtin_amdgcn_mfma_f32_16x16x32_bf16(a, b, c, 0, 0, 0);
  } else {
    return __builtin_amdgcn_mfma_f32_16x16x32_bf16(
        __builtin_bit_cast(bf16x8, a), __builtin_bit_cast(bf16x8, b), c, 0, 0, 0);
  }
}
#endif

// C[M,N] = A[M,K] @ B[K,N], fp32 accum. A/B fp32 or bf16 per template (fp32 is
// converted RNE->bf16 while staging into LDS); C stored bf16 or fp32 per CF32.
// 64x64 tile, BK=32, 256 threads (4 waves), wave w -> 16-row output stripe.
template <bool AF32, bool BF32, bool CF32>
__global__ __launch_bounds__(256) void gemm_mixed(const void* __restrict__ Ap,
                                                  const void* __restrict__ Bp,
                                                  void* __restrict__ Cp,
                                                  int M, int N, int K,
                                                  int lda, int ldb, int ldc) {
#if defined(__HIP_DEVICE_COMPILE__)
  __shared__ u16 As[64][40];  // [m][k], +8 pad
  __shared__ u16 Bs[64][40];  // [n][k] (transposed at stage), +8 pad
  const int tid = threadIdx.x;
  const int lane = tid & 63;
  const int w = tid >> 6;
  const int m0 = blockIdx.y * 64;
  const int n0 = blockIdx.x * 64;
  const int arow = tid >> 2, acol = (tid & 3) * 8;
  const int brow = tid >> 3, bcol = (tid & 7) * 8;
  const int ml = lane & 15, qd = lane >> 4;
  float4v acc[4] = {};
  for (int kk = 0; kk < K; kk += 32) {
    __syncthreads();
    if constexpr (AF32) {
      const float* A = (const float*)Ap;
      const float* src = A + (size_t)(m0 + arow) * lda + (kk + acol);
      float4 f0 = *(const float4*)src;
      float4 f1 = *(const float4*)(src + 4);
      alignas(16) u16 tmp[8] = {f2bf(f0.x), f2bf(f0.y), f2bf(f0.z), f2bf(f0.w),
                                f2bf(f1.x), f2bf(f1.y), f2bf(f1.z), f2bf(f1.w)};
      *(uint4*)(&As[arow][acol]) = *(const uint4*)tmp;
    } else {
      const u16* A = (const u16*)Ap;
      uint4 av = *(const uint4*)(A + (size_t)(m0 + arow) * lda + (kk + acol));
      *(uint4*)(&As[arow][acol]) = av;
    }
    if constexpr (BF32) {
      const float* Bm = (const float*)Bp;
      const float* src = Bm + (size_t)(kk + brow) * ldb + (n0 + bcol);
      float4 f0 = *(const float4*)src;
      float4 f1 = *(const float4*)(src + 4);
      float fv[8] = {f0.x, f0.y, f0.z, f0.w, f1.x, f1.y, f1.z, f1.w};
#pragma unroll
      for (int i = 0; i < 8; ++i) Bs[bcol + i][brow] = f2bf(fv[i]);
    } else {
      const u16* Bm = (const u16*)Bp;
      uint4 bv = *(const uint4*)(Bm + (size_t)(kk + brow) * ldb + (n0 + bcol));
      const u16* bsp = (const u16*)&bv;
#pragma unroll
      for (int i = 0; i < 8; ++i) Bs[bcol + i][brow] = bsp[i];
    }
    __syncthreads();
    short8 af = *(const short8*)(&As[w * 16 + ml][qd * 8]);
#pragma unroll
    for (int nt = 0; nt < 4; ++nt) {
      short8 bf = *(const short8*)(&Bs[nt * 16 + ml][qd * 8]);
      acc[nt] = mfma_bf16(af, bf, acc[nt]);
    }
  }
#pragma unroll
  for (int nt = 0; nt < 4; ++nt) {
#pragma unroll
    for (int r = 0; r < 4; ++r) {
      int row = m0 + w * 16 + qd * 4 + r;
      int col = n0 + nt * 16 + ml;
      if constexpr (CF32) {
        ((float*)Cp)[(size_t)row * ldc + col] = acc[nt][r];
      } else {
        ((u16*)Cp)[(size_t)row * ldc + col] = f2bf(acc[nt][r]);
      }
    }
  }
#endif
}

// In-place RoPE on qkv [B,T,3C] bf16.
__global__ __launch_bounds__(256) void rope_inplace(u16* __restrict__ qkv) {
  int idx = blockIdx.x * 256 + threadIdx.x;  // B*T*H*64 threads
  int d = idx & 63;
  int h = (idx >> 6) & 15;
  int t = (idx >> 10) & 2047;
  int b = idx >> 21;
  size_t row = (size_t)(b * T_ + t) * LDQKV;
  u16* qp = qkv + row + h * 128;
  u16* kp = qkv + row + C_ + h * 128;
  float q1 = bfbits2f(qp[d]);
  float q2 = bfbits2f(qp[d + 64]);
  float k1 = bfbits2f(kp[d]);
  float k2 = bfbits2f(kp[d + 64]);
  float invf = exp2f((float)d * -0.20762050593046012f);
  float fr = (float)t * invf;
  float sn, cs;
  sincosf(fr, &sn, &cs);
  qp[d] = f2bf(q1 * cs - q2 * sn);
  qp[d + 64] = f2bf(q2 * cs + q1 * sn);
  kp[d] = f2bf(k1 * cs - k2 * sn);
  kp[d + 64] = f2bf(k2 * cs + k1 * sn);
}

// MFMA flash attention. qkv [B,T,3C] bf16 (post-RoPE). Y written into Q cols.
// Block: 128 q-rows of one (b,h); 4 waves x 32 rows. Key chunks of 64.
// Grid 512 (1D): half/bh/q3 decode pairs long+short q-tiles across halves.
__global__ __launch_bounds__(256, 2) void attn_fwd(u16* __restrict__ qkv) {
#if defined(__HIP_DEVICE_COMPILE__)
  __shared__ alignas(16) u16 ks[64][136];   // K chunk, natural [key][d], +8 pad
  __shared__ alignas(16) u16 vt[128][72];   // V chunk transposed [d][key], +8 pad
  __shared__ alignas(16) u16 pb[4][32][72]; // per-wave P (C-layout -> A-layout)
  const int tid = threadIdx.x;
  const int lane = tid & 63;
  const int w = tid >> 6;
  const int ml = lane & 15, qd = lane >> 4;
  const int gx = blockIdx.x;
  const int half = gx >> 8;
  const int rem = gx & 255;
  const int bh = rem >> 3;
  const int q3 = rem & 7;
  const int qt = half ? q3 : (15 - q3);  // pair qt long+short across halves
  const int b = bh >> 4, h = bh & 15;
  const int hc = h * 128;
  const int m0 = qt * 128;
  const size_t rb = (size_t)(b * T_);
  // Q A-frags (held in registers for the whole block): qf[m][k4]
  short8 qf[2][4];
#pragma unroll
  for (int m = 0; m < 2; ++m) {
    const u16* qp = qkv + (rb + m0 + w * 32 + m * 16 + ml) * LDQKV + hc;
#pragma unroll
    for (int k4 = 0; k4 < 4; ++k4)
      qf[m][k4] = *(const short8*)(qp + k4 * 32 + qd * 8);
  }
  float4v acc[2][8] = {};
  float mi[2][4], li[2][4];
#pragma unroll
  for (int m = 0; m < 2; ++m)
#pragma unroll
    for (int r = 0; r < 4; ++r) { mi[m][r] = -1.0e30f; li[m][r] = 0.f; }
  const float scale = 0.08838834764831845f;  // 1/sqrt(128)
  const int srow = tid >> 2;
  const int scol = (tid & 3) * 32;
  const int nchunk = 2 * qt + 2;

  for (int c = 0; c < nchunk; ++c) {
    __syncthreads();
    {
      const u16* kp = qkv + (rb + c * 64 + srow) * LDQKV + C_ + hc + scol;
      const u16* vp = qkv + (rb + c * 64 + srow) * LDQKV + 2 * C_ + hc + scol;
#pragma unroll
      for (int i = 0; i < 4; ++i)
        *(uint4*)&ks[srow][scol + i * 8] = *(const uint4*)(kp + i * 8);
#pragma unroll
      for (int i = 0; i < 4; ++i) {
        uint4 vv = *(const uint4*)(vp + i * 8);
        const u16* e = (const u16*)&vv;
#pragma unroll
        for (int t = 0; t < 8; ++t) vt[scol + i * 8 + t][srow] = e[t];
      }
    }
    __syncthreads();
    if (c * 64 > m0 + w * 32 + 31) continue;  // wave fully masked (tail chunk)
    // ---- S = Q K^T : s[m][t] 16x16 tiles, t = key tile ----
    float4v s[2][4] = {};
#pragma unroll
    for (int t = 0; t < 4; ++t) {
#pragma unroll
      for (int k4 = 0; k4 < 4; ++k4) {
        short8 bf = *(const short8*)(&ks[t * 16 + ml][k4 * 32 + qd * 8]);
        s[0][t] = mfma_bf16(qf[0][k4], bf, s[0][t]);
        s[1][t] = mfma_bf16(qf[1][k4], bf, s[1][t]);
      }
    }
    // ---- online softmax (C-layout: col=ml within tile, row=qd*4+r) ----
    const bool domask = (c * 64 + 63) > (m0 + w * 32);
#pragma unroll
    for (int m = 0; m < 2; ++m) {
      float al[4];
#pragma unroll
      for (int r = 0; r < 4; ++r) {
        float x0 = s[m][0][r] * scale;
        float x1 = s[m][1][r] * scale;
        float x2 = s[m][2][r] * scale;
        float x3 = s[m][3][r] * scale;
        if (domask) {
          int row = m0 + w * 32 + m * 16 + qd * 4 + r;
          int j0 = c * 64 + ml;
          if (j0 > row) x0 = -1.0e30f;
          if (j0 + 16 > row) x1 = -1.0e30f;
          if (j0 + 32 > row) x2 = -1.0e30f;
          if (j0 + 48 > row) x3 = -1.0e30f;
        }
        float mx = fmaxf(fmaxf(x0, x1), fmaxf(x2, x3));
        mx = fmaxf(mx, __shfl_xor(mx, 1));
        mx = fmaxf(mx, __shfl_xor(mx, 2));
        mx = fmaxf(mx, __shfl_xor(mx, 4));
        mx = fmaxf(mx, __shfl_xor(mx, 8));
        float mnew = fmaxf(mi[m][r], mx);
        float a = __expf(mi[m][r] - mnew);
        float p0 = __expf(x0 - mnew);
        float p1 = __expf(x1 - mnew);
        float p2 = __expf(x2 - mnew);
        float p3 = __expf(x3 - mnew);
        float sm = p0 + p1 + p2 + p3;
        sm += __shfl_xor(sm, 1);
        sm += __shfl_xor(sm, 2);
        sm += __shfl_xor(sm, 4);
        sm += __shfl_xor(sm, 8);
        li[m][r] = li[m][r] * a + sm;
        mi[m][r] = mnew;
        al[r] = a;
        int prow = m * 16 + qd * 4 + r;
        pb[w][prow][ml] = f2bf(p0);
        pb[w][prow][16 + ml] = f2bf(p1);
        pb[w][prow][32 + ml] = f2bf(p2);
        pb[w][prow][48 + ml] = f2bf(p3);
      }
#pragma unroll
      for (int d = 0; d < 8; ++d) {
        acc[m][d][0] *= al[0];
        acc[m][d][1] *= al[1];
        acc[m][d][2] *= al[2];
        acc[m][d][3] *= al[3];
      }
    }
    // ---- O += P V ----
#pragma unroll
    for (int k2 = 0; k2 < 2; ++k2) {
      short8 pa0 = *(const short8*)(&pb[w][ml][k2 * 32 + qd * 8]);
      short8 pa1 = *(const short8*)(&pb[w][16 + ml][k2 * 32 + qd * 8]);
#pragma unroll
      for (int d = 0; d < 8; ++d) {
        short8 vf = *(const short8*)(&vt[d * 16 + ml][k2 * 32 + qd * 8]);
        acc[0][d] = mfma_bf16(pa0, vf, acc[0][d]);
        acc[1][d] = mfma_bf16(pa1, vf, acc[1][d]);
      }
    }
  }
  // ---- epilogue: O/l -> Q columns of qkv ----
#pragma unroll
  for (int m = 0; m < 2; ++m) {
#pragma unroll
    for (int r = 0; r < 4; ++r) {
      float inv = 1.0f / li[m][r];
      size_t row = rb + m0 + w * 32 + m * 16 + qd * 4 + r;
#pragma unroll
      for (int d = 0; d < 8; ++d)
        qkv[row * LDQKV + hc + d * 16 + ml] = f2bf(acc[m][d][r] * inv);
    }
  }
#endif
}

extern "C" void kernel_launch(void* const* d_in, const int* in_sizes, int n_in,
                              void* d_out, int out_size, void* d_ws, size_t ws_size,
                              hipStream_t stream) {
  const float* x = (const float*)d_in[0];     // [B,T,C] fp32
  const float* wqkv = (const float*)d_in[1];  // [C,3C] fp32
  const float* wout = (const float*)d_in[2];  // [C,C] fp32
  float* out = (float*)d_out;                 // [B,T,C] fp32
  u16* qkv = (u16*)d_ws;                      // [B*T, 3C] bf16 (48 MB)

  gemm_mixed<true, true, false><<<dim3(96, 64), dim3(256), 0, stream>>>(
      x, wqkv, qkv, 4096, 6144, 2048, 2048, 6144, 6144);
  rope_inplace<<<dim3(16384), dim3(256), 0, stream>>>(qkv);
  attn_fwd<<<dim3(512), dim3(256), 0, stream>>>(qkv);
  gemm_mixed<false, true, true><<<dim3(32, 64), dim3(256), 0, stream>>>(
      qkv, wout, out, 4096, 2048, 2048, 6144, 2048, 2048);
}

// Round 5
// 494.921 us; speedup vs baseline: 5.4416x; 1.9184x over previous
//
#include <hip/hip_runtime.h>
#include <hip/hip_bf16.h>
#include <type_traits>
#include <utility>

typedef unsigned short u16;
typedef unsigned int u32;

#define B_ 2
#define T_ 2048
#define C_ 2048
#define H_ 16
#define D_ 128
#define LDQKV 6144  // row stride of qkv [B*T, 3C]

typedef float float4v __attribute__((ext_vector_type(4)));
typedef short short8 __attribute__((ext_vector_type(8)));

__device__ inline u16 f2bf(float f) {
  u32 u = __builtin_bit_cast(u32, f);
  u32 r = u + 0x7fffu + ((u >> 16) & 1u);  // RNE
  return (u16)(r >> 16);
}
__device__ inline float bfbits2f(u16 b) {
  return __builtin_bit_cast(float, (u32)b << 16);
}

#if defined(__HIP_DEVICE_COMPILE__)
typedef __bf16 bf16x8 __attribute__((ext_vector_type(8)));

template <typename V, typename = void>
struct mfma_takes_short : std::false_type {};
template <typename V>
struct mfma_takes_short<V, std::void_t<decltype(__builtin_amdgcn_mfma_f32_16x16x32_bf16(
    std::declval<V>(), std::declval<V>(), std::declval<float4v>(), 0, 0, 0))>>
    : std::true_type {};

template <typename SV>
__device__ inline float4v mfma_bf16(SV a, SV b, float4v c) {
  if constexpr (mfma_takes_short<SV>::value) {
    return __builtin_amdgcn_mfma_f32_16x16x32_bf16(a, b, c, 0, 0, 0);
  } else {
    return __builtin_amdgcn_mfma_f32_16x16x32_bf16(
        __builtin_bit_cast(bf16x8, a), __builtin_bit_cast(bf16x8, b), c, 0, 0, 0);
  }
}

// Async global->LDS, 16B/lane. LDS dest = wave-uniform base + lane*16.
__device__ inline void async16(u16* lds, const u16* g) {
  typedef __attribute__((address_space(3))) void lds_void;
  typedef __attribute__((address_space(1))) const void g_void;
  __builtin_amdgcn_global_load_lds((g_void*)g, (lds_void*)lds, 16, 0, 0);
}
#endif

// ---------------- pre-cast kernels ----------------
// fp32 -> bf16, flat, 4 elems/thread.
__global__ __launch_bounds__(256) void cast_f32_bf16(const float* __restrict__ s,
                                                     u16* __restrict__ d) {
  int i = (blockIdx.x * 256 + threadIdx.x) * 4;
  float4 v = *(const float4*)(s + i);
  alignas(8) u16 o[4] = {f2bf(v.x), f2bf(v.y), f2bf(v.z), f2bf(v.w)};
  *(uint2*)(d + i) = *(const uint2*)o;
}

// src [R,Cc] fp32 row-major -> dst [Cc,R] bf16 row-major (cast + transpose).
__global__ __launch_bounds__(256) void castT_f32_bf16(const float* __restrict__ src,
                                                      u16* __restrict__ dst,
                                                      int R, int Cc) {
  __shared__ float tile[32][33];
  const int t = threadIdx.x;
  const int r0 = blockIdx.y * 32, c0 = blockIdx.x * 32;
  const int lr = t >> 3, lc = (t & 7) * 4;
  float4 v = *(const float4*)(src + (size_t)(r0 + lr) * Cc + c0 + lc);
  tile[lr][lc + 0] = v.x;
  tile[lr][lc + 1] = v.y;
  tile[lr][lc + 2] = v.z;
  tile[lr][lc + 3] = v.w;
  __syncthreads();
  alignas(8) u16 o[4];
#pragma unroll
  for (int j = 0; j < 4; ++j) o[j] = f2bf(tile[lc + j][lr]);
  *(uint2*)(dst + (size_t)(c0 + lr) * R + r0 + lc) = *(const uint2*)o;
}

// ---------------- m97-style GEMM ----------------
// C[M,N] = A[M,K] @ BT[N,K]^T, A/BT bf16 row-major. 128x128 tile, BK=32,
// 256 threads = 4 waves (2x2), each wave 64x64 (4x4 of 16x16x32 MFMA).
// Staging via global_load_lds width16; LDS layout lane-contiguous [m][k] / [n][k].
template <bool CF32>
__global__ __launch_bounds__(256) void gemm_bt(const u16* __restrict__ A,
                                               const u16* __restrict__ BT,
                                               void* __restrict__ Cp,
                                               int K, int lda, int ldbt, int ldc) {
#if defined(__HIP_DEVICE_COMPILE__)
  __shared__ u16 As[4096];  // 128x32 [m][k] linear
  __shared__ u16 Bs[4096];  // 128x32 [n][k] linear
  const int tid = threadIdx.x;
  const int lane = tid & 63;
  const int w = tid >> 6;
  const int wm = w & 1, wn = w >> 1;
  const int ml = lane & 15, qd = lane >> 4;
  const int m0 = blockIdx.y * 128, n0 = blockIdx.x * 128;
  const int sm = lane >> 2, sk = (lane & 3) * 8;
  const u16* gA[2];
  const u16* gB[2];
  u16 *lA[2], *lB[2];
#pragma unroll
  for (int r = 0; r < 2; ++r) {
    int seg = r * 4 + w;
    gA[r] = A + (size_t)(m0 + seg * 16 + sm) * lda + sk;
    gB[r] = BT + (size_t)(n0 + seg * 16 + sm) * ldbt + sk;
    lA[r] = As + seg * 512;
    lB[r] = Bs + seg * 512;
  }
  float4v acc[4][4] = {};
  for (int kk = 0; kk < K; kk += 32) {
    __syncthreads();
    async16(lA[0], gA[0] + kk);
    async16(lA[1], gA[1] + kk);
    async16(lB[0], gB[0] + kk);
    async16(lB[1], gB[1] + kk);
    __syncthreads();  // compiler emits vmcnt(0) drain before barrier
    short8 a[4], b[4];
#pragma unroll
    for (int mt = 0; mt < 4; ++mt)
      a[mt] = *(const short8*)(As + (wm * 64 + mt * 16 + ml) * 32 + qd * 8);
#pragma unroll
    for (int nt = 0; nt < 4; ++nt)
      b[nt] = *(const short8*)(Bs + (wn * 64 + nt * 16 + ml) * 32 + qd * 8);
#pragma unroll
    for (int mt = 0; mt < 4; ++mt)
#pragma unroll
      for (int nt = 0; nt < 4; ++nt) acc[mt][nt] = mfma_bf16(a[mt], b[nt], acc[mt][nt]);
  }
  // C/D: col=ml, row=qd*4+r within each 16x16 tile
#pragma unroll
  for (int mt = 0; mt < 4; ++mt) {
#pragma unroll
    for (int nt = 0; nt < 4; ++nt) {
#pragma unroll
      for (int r = 0; r < 4; ++r) {
        int row = m0 + wm * 64 + mt * 16 + qd * 4 + r;
        int col = n0 + wn * 64 + nt * 16 + ml;
        if constexpr (CF32) {
          ((float*)Cp)[(size_t)row * ldc + col] = acc[mt][nt][r];
        } else {
          ((u16*)Cp)[(size_t)row * ldc + col] = f2bf(acc[mt][nt][r]);
        }
      }
    }
  }
#endif
}

// ---------------- fallback GEMM (round-3 path, used if ws too small) ----------------
template <bool AF32, bool BF32, bool CF32>
__global__ __launch_bounds__(256) void gemm_mixed(const void* __restrict__ Ap,
                                                  const void* __restrict__ Bp,
                                                  void* __restrict__ Cp,
                                                  int M, int N, int K,
                                                  int lda, int ldb, int ldc) {
#if defined(__HIP_DEVICE_COMPILE__)
  __shared__ u16 As[64][40];
  __shared__ u16 Bs[64][40];
  const int tid = threadIdx.x;
  const int lane = tid & 63;
  const int w = tid >> 6;
  const int m0 = blockIdx.y * 64;
  const int n0 = blockIdx.x * 64;
  const int arow = tid >> 2, acol = (tid & 3) * 8;
  const int brow = tid >> 3, bcol = (tid & 7) * 8;
  const int ml = lane & 15, qd = lane >> 4;
  float4v acc[4] = {};
  for (int kk = 0; kk < K; kk += 32) {
    __syncthreads();
    if constexpr (AF32) {
      const float* A = (const float*)Ap;
      const float* src = A + (size_t)(m0 + arow) * lda + (kk + acol);
      float4 f0 = *(const float4*)src;
      float4 f1 = *(const float4*)(src + 4);
      alignas(16) u16 tmp[8] = {f2bf(f0.x), f2bf(f0.y), f2bf(f0.z), f2bf(f0.w),
                                f2bf(f1.x), f2bf(f1.y), f2bf(f1.z), f2bf(f1.w)};
      *(uint4*)(&As[arow][acol]) = *(const uint4*)tmp;
    } else {
      const u16* A = (const u16*)Ap;
      *(uint4*)(&As[arow][acol]) = *(const uint4*)(A + (size_t)(m0 + arow) * lda + (kk + acol));
    }
    if constexpr (BF32) {
      const float* Bm = (const float*)Bp;
      const float* src = Bm + (size_t)(kk + brow) * ldb + (n0 + bcol);
      float4 f0 = *(const float4*)src;
      float4 f1 = *(const float4*)(src + 4);
      float fv[8] = {f0.x, f0.y, f0.z, f0.w, f1.x, f1.y, f1.z, f1.w};
#pragma unroll
      for (int i = 0; i < 8; ++i) Bs[bcol + i][brow] = f2bf(fv[i]);
    } else {
      const u16* Bm = (const u16*)Bp;
      uint4 bv = *(const uint4*)(Bm + (size_t)(kk + brow) * ldb + (n0 + bcol));
      const u16* bsp = (const u16*)&bv;
#pragma unroll
      for (int i = 0; i < 8; ++i) Bs[bcol + i][brow] = bsp[i];
    }
    __syncthreads();
    short8 af = *(const short8*)(&As[w * 16 + ml][qd * 8]);
#pragma unroll
    for (int nt = 0; nt < 4; ++nt) {
      short8 bf = *(const short8*)(&Bs[nt * 16 + ml][qd * 8]);
      acc[nt] = mfma_bf16(af, bf, acc[nt]);
    }
  }
#pragma unroll
  for (int nt = 0; nt < 4; ++nt) {
#pragma unroll
    for (int r = 0; r < 4; ++r) {
      int row = m0 + w * 16 + qd * 4 + r;
      int col = n0 + nt * 16 + ml;
      if constexpr (CF32) {
        ((float*)Cp)[(size_t)row * ldc + col] = acc[nt][r];
      } else {
        ((u16*)Cp)[(size_t)row * ldc + col] = f2bf(acc[nt][r]);
      }
    }
  }
#endif
}

// In-place RoPE on qkv [B,T,3C] bf16.
__global__ __launch_bounds__(256) void rope_inplace(u16* __restrict__ qkv) {
  int idx = blockIdx.x * 256 + threadIdx.x;
  int d = idx & 63;
  int h = (idx >> 6) & 15;
  int t = (idx >> 10) & 2047;
  int b = idx >> 21;
  size_t row = (size_t)(b * T_ + t) * LDQKV;
  u16* qp = qkv + row + h * 128;
  u16* kp = qkv + row + C_ + h * 128;
  float q1 = bfbits2f(qp[d]);
  float q2 = bfbits2f(qp[d + 64]);
  float k1 = bfbits2f(kp[d]);
  float k2 = bfbits2f(kp[d + 64]);
  float invf = exp2f((float)d * -0.20762050593046012f);
  float fr = (float)t * invf;
  float sn, cs;
  sincosf(fr, &sn, &cs);
  qp[d] = f2bf(q1 * cs - q2 * sn);
  qp[d + 64] = f2bf(q2 * cs + q1 * sn);
  kp[d] = f2bf(k1 * cs - k2 * sn);
  kp[d + 64] = f2bf(k2 * cs + k1 * sn);
}

// MFMA flash attention (round-4, unchanged). qkv bf16 post-RoPE; Y -> Q cols.
__global__ __launch_bounds__(256, 2) void attn_fwd(u16* __restrict__ qkv) {
#if defined(__HIP_DEVICE_COMPILE__)
  __shared__ alignas(16) u16 ks[64][136];
  __shared__ alignas(16) u16 vt[128][72];
  __shared__ alignas(16) u16 pb[4][32][72];
  const int tid = threadIdx.x;
  const int lane = tid & 63;
  const int w = tid >> 6;
  const int ml = lane & 15, qd = lane >> 4;
  const int gx = blockIdx.x;
  const int half = gx >> 8;
  const int rem = gx & 255;
  const int bh = rem >> 3;
  const int q3 = rem & 7;
  const int qt = half ? q3 : (15 - q3);
  const int b = bh >> 4, h = bh & 15;
  const int hc = h * 128;
  const int m0 = qt * 128;
  const size_t rb = (size_t)(b * T_);
  short8 qf[2][4];
#pragma unroll
  for (int m = 0; m < 2; ++m) {
    const u16* qp = qkv + (rb + m0 + w * 32 + m * 16 + ml) * LDQKV + hc;
#pragma unroll
    for (int k4 = 0; k4 < 4; ++k4) qf[m][k4] = *(const short8*)(qp + k4 * 32 + qd * 8);
  }
  float4v acc[2][8] = {};
  float mi[2][4], li[2][4];
#pragma unroll
  for (int m = 0; m < 2; ++m)
#pragma unroll
    for (int r = 0; r < 4; ++r) { mi[m][r] = -1.0e30f; li[m][r] = 0.f; }
  const float scale = 0.08838834764831845f;
  const int srow = tid >> 2;
  const int scol = (tid & 3) * 32;
  const int nchunk = 2 * qt + 2;

  for (int c = 0; c < nchunk; ++c) {
    __syncthreads();
    {
      const u16* kp = qkv + (rb + c * 64 + srow) * LDQKV + C_ + hc + scol;
      const u16* vp = qkv + (rb + c * 64 + srow) * LDQKV + 2 * C_ + hc + scol;
#pragma unroll
      for (int i = 0; i < 4; ++i)
        *(uint4*)&ks[srow][scol + i * 8] = *(const uint4*)(kp + i * 8);
#pragma unroll
      for (int i = 0; i < 4; ++i) {
        uint4 vv = *(const uint4*)(vp + i * 8);
        const u16* e = (const u16*)&vv;
#pragma unroll
        for (int t = 0; t < 8; ++t) vt[scol + i * 8 + t][srow] = e[t];
      }
    }
    __syncthreads();
    if (c * 64 > m0 + w * 32 + 31) continue;
    float4v s[2][4] = {};
#pragma unroll
    for (int t = 0; t < 4; ++t) {
#pragma unroll
      for (int k4 = 0; k4 < 4; ++k4) {
        short8 bf = *(const short8*)(&ks[t * 16 + ml][k4 * 32 + qd * 8]);
        s[0][t] = mfma_bf16(qf[0][k4], bf, s[0][t]);
        s[1][t] = mfma_bf16(qf[1][k4], bf, s[1][t]);
      }
    }
    const bool domask = (c * 64 + 63) > (m0 + w * 32);
#pragma unroll
    for (int m = 0; m < 2; ++m) {
      float al[4];
#pragma unroll
      for (int r = 0; r < 4; ++r) {
        float x0 = s[m][0][r] * scale;
        float x1 = s[m][1][r] * scale;
        float x2 = s[m][2][r] * scale;
        float x3 = s[m][3][r] * scale;
        if (domask) {
          int row = m0 + w * 32 + m * 16 + qd * 4 + r;
          int j0 = c * 64 + ml;
          if (j0 > row) x0 = -1.0e30f;
          if (j0 + 16 > row) x1 = -1.0e30f;
          if (j0 + 32 > row) x2 = -1.0e30f;
          if (j0 + 48 > row) x3 = -1.0e30f;
        }
        float mx = fmaxf(fmaxf(x0, x1), fmaxf(x2, x3));
        mx = fmaxf(mx, __shfl_xor(mx, 1));
        mx = fmaxf(mx, __shfl_xor(mx, 2));
        mx = fmaxf(mx, __shfl_xor(mx, 4));
        mx = fmaxf(mx, __shfl_xor(mx, 8));
        float mnew = fmaxf(mi[m][r], mx);
        float a = __expf(mi[m][r] - mnew);
        float p0 = __expf(x0 - mnew);
        float p1 = __expf(x1 - mnew);
        float p2 = __expf(x2 - mnew);
        float p3 = __expf(x3 - mnew);
        float sm = p0 + p1 + p2 + p3;
        sm += __shfl_xor(sm, 1);
        sm += __shfl_xor(sm, 2);
        sm += __shfl_xor(sm, 4);
        sm += __shfl_xor(sm, 8);
        li[m][r] = li[m][r] * a + sm;
        mi[m][r] = mnew;
        al[r] = a;
        int prow = m * 16 + qd * 4 + r;
        pb[w][prow][ml] = f2bf(p0);
        pb[w][prow][16 + ml] = f2bf(p1);
        pb[w][prow][32 + ml] = f2bf(p2);
        pb[w][prow][48 + ml] = f2bf(p3);
      }
#pragma unroll
      for (int d = 0; d < 8; ++d) {
        acc[m][d][0] *= al[0];
        acc[m][d][1] *= al[1];
        acc[m][d][2] *= al[2];
        acc[m][d][3] *= al[3];
      }
    }
#pragma unroll
    for (int k2 = 0; k2 < 2; ++k2) {
      short8 pa0 = *(const short8*)(&pb[w][ml][k2 * 32 + qd * 8]);
      short8 pa1 = *(const short8*)(&pb[w][16 + ml][k2 * 32 + qd * 8]);
#pragma unroll
      for (int d = 0; d < 8; ++d) {
        short8 vf = *(const short8*)(&vt[d * 16 + ml][k2 * 32 + qd * 8]);
        acc[0][d] = mfma_bf16(pa0, vf, acc[0][d]);
        acc[1][d] = mfma_bf16(pa1, vf, acc[1][d]);
      }
    }
  }
#pragma unroll
  for (int m = 0; m < 2; ++m) {
#pragma unroll
    for (int r = 0; r < 4; ++r) {
      float inv = 1.0f / li[m][r];
      size_t row = rb + m0 + w * 32 + m * 16 + qd * 4 + r;
#pragma unroll
      for (int d = 0; d < 8; ++d)
        qkv[row * LDQKV + hc + d * 16 + ml] = f2bf(acc[m][d][r] * inv);
    }
  }
#endif
}

extern "C" void kernel_launch(void* const* d_in, const int* in_sizes, int n_in,
                              void* d_out, int out_size, void* d_ws, size_t ws_size,
                              hipStream_t stream) {
  const float* x = (const float*)d_in[0];     // [B,T,C] fp32
  const float* wqkv = (const float*)d_in[1];  // [C,3C] fp32
  const float* wout = (const float*)d_in[2];  // [C,C] fp32
  float* out = (float*)d_out;                 // [B,T,C] fp32
  char* ws = (char*)d_ws;
  u16* qkv = (u16*)ws;  // [4096, 6144] bf16 = 48 MB; Q cols reused as Y

  const size_t MB = 1024 * 1024;
  if (ws_size >= 96 * MB) {
    // fast path: pre-cast to bf16 (+transpose weights), m97-style GEMMs
    u16* xb = (u16*)(ws + 48 * MB);      // [4096,2048] bf16, 16 MB
    u16* wqkvT = (u16*)(ws + 64 * MB);   // [6144,2048] bf16, 24 MB
    u16* woutT = (u16*)(ws + 88 * MB);   // [2048,2048] bf16, 8 MB
    cast_f32_bf16<<<dim3(8192), dim3(256), 0, stream>>>(x, xb);
    castT_f32_bf16<<<dim3(192, 64), dim3(256), 0, stream>>>(wqkv, wqkvT, 2048, 6144);
    castT_f32_bf16<<<dim3(64, 64), dim3(256), 0, stream>>>(wout, woutT, 2048, 2048);
    gemm_bt<false><<<dim3(48, 32), dim3(256), 0, stream>>>(
        xb, wqkvT, qkv, 2048, 2048, 2048, 6144);
    rope_inplace<<<dim3(16384), dim3(256), 0, stream>>>(qkv);
    attn_fwd<<<dim3(512), dim3(256), 0, stream>>>(qkv);
    gemm_bt<true><<<dim3(16, 32), dim3(256), 0, stream>>>(
        qkv, woutT, out, 2048, 6144, 2048, 2048);
  } else {
    // fallback: round-3 structure (48 MB ws)
    gemm_mixed<true, true, false><<<dim3(96, 64), dim3(256), 0, stream>>>(
        x, wqkv, qkv, 4096, 6144, 2048, 2048, 6144, 6144);
    rope_inplace<<<dim3(16384), dim3(256), 0, stream>>>(qkv);
    attn_fwd<<<dim3(512), dim3(256), 0, stream>>>(qkv);
    gemm_mixed<false, true, true><<<dim3(32, 64), dim3(256), 0, stream>>>(
        qkv, wout, out, 4096, 2048, 2048, 6144, 2048, 2048);
  }
}

// Round 6
// 429.444 us; speedup vs baseline: 6.2713x; 1.1525x over previous
//
#include <hip/hip_runtime.h>
#include <hip/hip_bf16.h>
#include <type_traits>
#include <utility>

typedef unsigned short u16;
typedef unsigned int u32;

#define B_ 2
#define T_ 2048
#define C_ 2048
#define H_ 16
#define D_ 128
#define LDQKV 6144  // row stride of qkv [B*T, 3C]

typedef float float4v __attribute__((ext_vector_type(4)));
typedef short short8 __attribute__((ext_vector_type(8)));

__device__ inline u16 f2bf(float f) {
  u32 u = __builtin_bit_cast(u32, f);
  u32 r = u + 0x7fffu + ((u >> 16) & 1u);  // RNE
  return (u16)(r >> 16);
}
__device__ inline float bfbits2f(u16 b) {
  return __builtin_bit_cast(float, (u32)b << 16);
}
// pack two floats to bf16 pair (round-half-up; cheap, used for softmax P)
__device__ inline u32 pack2bf(float a, float b) {
  u32 ua = (__builtin_bit_cast(u32, a) + 0x8000u) >> 16;
  u32 ub = (__builtin_bit_cast(u32, b) + 0x8000u) & 0xffff0000u;
  return ua | ub;
}

#if defined(__HIP_DEVICE_COMPILE__)
typedef __bf16 bf16x8 __attribute__((ext_vector_type(8)));

template <typename V, typename = void>
struct mfma_takes_short : std::false_type {};
template <typename V>
struct mfma_takes_short<V, std::void_t<decltype(__builtin_amdgcn_mfma_f32_16x16x32_bf16(
    std::declval<V>(), std::declval<V>(), std::declval<float4v>(), 0, 0, 0))>>
    : std::true_type {};

template <typename SV>
__device__ inline float4v mfma_bf16(SV a, SV b, float4v c) {
  if constexpr (mfma_takes_short<SV>::value) {
    return __builtin_amdgcn_mfma_f32_16x16x32_bf16(a, b, c, 0, 0, 0);
  } else {
    return __builtin_amdgcn_mfma_f32_16x16x32_bf16(
        __builtin_bit_cast(bf16x8, a), __builtin_bit_cast(bf16x8, b), c, 0, 0, 0);
  }
}

// Async global->LDS, 16B/lane. LDS dest = wave-uniform base + lane*16.
__device__ inline void async16(u16* lds, const u16* g) {
  typedef __attribute__((address_space(3))) void lds_void;
  typedef __attribute__((address_space(1))) const void g_void;
  __builtin_amdgcn_global_load_lds((g_void*)g, (lds_void*)lds, 16, 0, 0);
}
#endif

// ---------------- pre-cast kernels ----------------
__global__ __launch_bounds__(256) void cast_f32_bf16(const float* __restrict__ s,
                                                     u16* __restrict__ d) {
  int i = (blockIdx.x * 256 + threadIdx.x) * 4;
  float4 v = *(const float4*)(s + i);
  alignas(8) u16 o[4] = {f2bf(v.x), f2bf(v.y), f2bf(v.z), f2bf(v.w)};
  *(uint2*)(d + i) = *(const uint2*)o;
}

// src [R,Cc] fp32 row-major -> dst [Cc,R] bf16 row-major (cast + transpose).
__global__ __launch_bounds__(256) void castT_f32_bf16(const float* __restrict__ src,
                                                      u16* __restrict__ dst,
                                                      int R, int Cc) {
  __shared__ float tile[32][33];
  const int t = threadIdx.x;
  const int r0 = blockIdx.y * 32, c0 = blockIdx.x * 32;
  const int lr = t >> 3, lc = (t & 7) * 4;
  float4 v = *(const float4*)(src + (size_t)(r0 + lr) * Cc + c0 + lc);
  tile[lr][lc + 0] = v.x;
  tile[lr][lc + 1] = v.y;
  tile[lr][lc + 2] = v.z;
  tile[lr][lc + 3] = v.w;
  __syncthreads();
  alignas(8) u16 o[4];
#pragma unroll
  for (int j = 0; j < 4; ++j) o[j] = f2bf(tile[lc + j][lr]);
  *(uint2*)(dst + (size_t)(c0 + lr) * R + r0 + lc) = *(const uint2*)o;
}

// V columns of qkv -> Vt [BH, 128, 2048] bf16 (per-head transpose).
__global__ __launch_bounds__(256) void vT_build(const u16* __restrict__ qkv,
                                                u16* __restrict__ Vt) {
  __shared__ u16 lt[64][72];
  const int tid = threadIdx.x;
  const int bh = blockIdx.x;  // 32
  const int tt = blockIdx.y;  // 32 t-tiles of 64
  const int dd = blockIdx.z;  // 2 d-tiles of 64
  const int b = bh >> 4, h = bh & 15;
  const int r = tid >> 2;
  const int c4 = (tid & 3) * 16;
  const u16* src = qkv + ((size_t)(b * T_ + tt * 64 + r)) * LDQKV + 2 * C_ + h * 128 + dd * 64 + c4;
  *(uint4*)&lt[r][c4] = *(const uint4*)src;
  *(uint4*)&lt[r][c4 + 8] = *(const uint4*)(src + 8);
  __syncthreads();
  alignas(16) u16 o[16];
#pragma unroll
  for (int j = 0; j < 16; ++j) o[j] = lt[c4 + j][r];
  u16* dst = Vt + ((size_t)(bh * 128 + dd * 64 + r)) * 2048 + tt * 64 + c4;
  *(uint4*)dst = *(const uint4*)o;
  *(uint4*)(dst + 8) = *(const uint4*)(o + 8);
}

// ---------------- m97-style GEMM ----------------
template <bool CF32>
__global__ __launch_bounds__(256) void gemm_bt(const u16* __restrict__ A,
                                               const u16* __restrict__ BT,
                                               void* __restrict__ Cp,
                                               int K, int lda, int ldbt, int ldc) {
#if defined(__HIP_DEVICE_COMPILE__)
  __shared__ u16 As[4096];  // 128x32 [m][k] linear
  __shared__ u16 Bs[4096];  // 128x32 [n][k] linear
  const int tid = threadIdx.x;
  const int lane = tid & 63;
  const int w = tid >> 6;
  const int wm = w & 1, wn = w >> 1;
  const int ml = lane & 15, qd = lane >> 4;
  const int m0 = blockIdx.y * 128, n0 = blockIdx.x * 128;
  const int sm = lane >> 2, sk = (lane & 3) * 8;
  const u16* gA[2];
  const u16* gB[2];
  u16 *lA[2], *lB[2];
#pragma unroll
  for (int r = 0; r < 2; ++r) {
    int seg = r * 4 + w;
    gA[r] = A + (size_t)(m0 + seg * 16 + sm) * lda + sk;
    gB[r] = BT + (size_t)(n0 + seg * 16 + sm) * ldbt + sk;
    lA[r] = As + seg * 512;
    lB[r] = Bs + seg * 512;
  }
  float4v acc[4][4] = {};
  for (int kk = 0; kk < K; kk += 32) {
    __syncthreads();
    async16(lA[0], gA[0] + kk);
    async16(lA[1], gA[1] + kk);
    async16(lB[0], gB[0] + kk);
    async16(lB[1], gB[1] + kk);
    __syncthreads();
    short8 a[4], b[4];
#pragma unroll
    for (int mt = 0; mt < 4; ++mt)
      a[mt] = *(const short8*)(As + (wm * 64 + mt * 16 + ml) * 32 + qd * 8);
#pragma unroll
    for (int nt = 0; nt < 4; ++nt)
      b[nt] = *(const short8*)(Bs + (wn * 64 + nt * 16 + ml) * 32 + qd * 8);
#pragma unroll
    for (int mt = 0; mt < 4; ++mt)
#pragma unroll
      for (int nt = 0; nt < 4; ++nt) acc[mt][nt] = mfma_bf16(a[mt], b[nt], acc[mt][nt]);
  }
#pragma unroll
  for (int mt = 0; mt < 4; ++mt) {
#pragma unroll
    for (int nt = 0; nt < 4; ++nt) {
#pragma unroll
      for (int r = 0; r < 4; ++r) {
        int row = m0 + wm * 64 + mt * 16 + qd * 4 + r;
        int col = n0 + wn * 64 + nt * 16 + ml;
        if constexpr (CF32) {
          ((float*)Cp)[(size_t)row * ldc + col] = acc[mt][nt][r];
        } else {
          ((u16*)Cp)[(size_t)row * ldc + col] = f2bf(acc[mt][nt][r]);
        }
      }
    }
  }
#endif
}

// ---------------- fallback GEMM ----------------
template <bool AF32, bool BF32, bool CF32>
__global__ __launch_bounds__(256) void gemm_mixed(const void* __restrict__ Ap,
                                                  const void* __restrict__ Bp,
                                                  void* __restrict__ Cp,
                                                  int M, int N, int K,
                                                  int lda, int ldb, int ldc) {
#if defined(__HIP_DEVICE_COMPILE__)
  __shared__ u16 As[64][40];
  __shared__ u16 Bs[64][40];
  const int tid = threadIdx.x;
  const int lane = tid & 63;
  const int w = tid >> 6;
  const int m0 = blockIdx.y * 64;
  const int n0 = blockIdx.x * 64;
  const int arow = tid >> 2, acol = (tid & 3) * 8;
  const int brow = tid >> 3, bcol = (tid & 7) * 8;
  const int ml = lane & 15, qd = lane >> 4;
  float4v acc[4] = {};
  for (int kk = 0; kk < K; kk += 32) {
    __syncthreads();
    if constexpr (AF32) {
      const float* A = (const float*)Ap;
      const float* src = A + (size_t)(m0 + arow) * lda + (kk + acol);
      float4 f0 = *(const float4*)src;
      float4 f1 = *(const float4*)(src + 4);
      alignas(16) u16 tmp[8] = {f2bf(f0.x), f2bf(f0.y), f2bf(f0.z), f2bf(f0.w),
                                f2bf(f1.x), f2bf(f1.y), f2bf(f1.z), f2bf(f1.w)};
      *(uint4*)(&As[arow][acol]) = *(const uint4*)tmp;
    } else {
      const u16* A = (const u16*)Ap;
      *(uint4*)(&As[arow][acol]) = *(const uint4*)(A + (size_t)(m0 + arow) * lda + (kk + acol));
    }
    if constexpr (BF32) {
      const float* Bm = (const float*)Bp;
      const float* src = Bm + (size_t)(kk + brow) * ldb + (n0 + bcol);
      float4 f0 = *(const float4*)src;
      float4 f1 = *(const float4*)(src + 4);
      float fv[8] = {f0.x, f0.y, f0.z, f0.w, f1.x, f1.y, f1.z, f1.w};
#pragma unroll
      for (int i = 0; i < 8; ++i) Bs[bcol + i][brow] = f2bf(fv[i]);
    } else {
      const u16* Bm = (const u16*)Bp;
      uint4 bv = *(const uint4*)(Bm + (size_t)(kk + brow) * ldb + (n0 + bcol));
      const u16* bsp = (const u16*)&bv;
#pragma unroll
      for (int i = 0; i < 8; ++i) Bs[bcol + i][brow] = bsp[i];
    }
    __syncthreads();
    short8 af = *(const short8*)(&As[w * 16 + ml][qd * 8]);
#pragma unroll
    for (int nt = 0; nt < 4; ++nt) {
      short8 bf = *(const short8*)(&Bs[nt * 16 + ml][qd * 8]);
      acc[nt] = mfma_bf16(af, bf, acc[nt]);
    }
  }
#pragma unroll
  for (int nt = 0; nt < 4; ++nt) {
#pragma unroll
    for (int r = 0; r < 4; ++r) {
      int row = m0 + w * 16 + qd * 4 + r;
      int col = n0 + nt * 16 + ml;
      if constexpr (CF32) {
        ((float*)Cp)[(size_t)row * ldc + col] = acc[nt][r];
      } else {
        ((u16*)Cp)[(size_t)row * ldc + col] = f2bf(acc[nt][r]);
      }
    }
  }
#endif
}

// In-place RoPE on qkv [B,T,3C] bf16; q additionally scaled by qscale.
__global__ __launch_bounds__(256) void rope_inplace(u16* __restrict__ qkv, float qscale) {
  int idx = blockIdx.x * 256 + threadIdx.x;
  int d = idx & 63;
  int h = (idx >> 6) & 15;
  int t = (idx >> 10) & 2047;
  int b = idx >> 21;
  size_t row = (size_t)(b * T_ + t) * LDQKV;
  u16* qp = qkv + row + h * 128;
  u16* kp = qkv + row + C_ + h * 128;
  float q1 = bfbits2f(qp[d]);
  float q2 = bfbits2f(qp[d + 64]);
  float k1 = bfbits2f(kp[d]);
  float k2 = bfbits2f(kp[d + 64]);
  float invf = exp2f((float)d * -0.20762050593046012f);
  float fr = (float)t * invf;
  float sn, cs;
  sincosf(fr, &sn, &cs);
  qp[d] = f2bf((q1 * cs - q2 * sn) * qscale);
  qp[d + 64] = f2bf((q2 * cs + q1 * sn) * qscale);
  kp[d] = f2bf(k1 * cs - k2 * sn);
  kp[d + 64] = f2bf(k2 * cs + k1 * sn);
}

// MFMA flash attention v2: S^T = K Q^T orientation, async swizzled staging.
// Q pre-scaled by 1/sqrt(D) in rope. Block: 128 q-rows of one (b,h); 4 waves
// x 32 q-rows. Key chunks of 64. Y -> Q cols of qkv.
__global__ __launch_bounds__(256, 2) void attn_fwd2(u16* __restrict__ qkv,
                                                    const u16* __restrict__ Vt) {
#if defined(__HIP_DEVICE_COMPILE__)
  __shared__ alignas(16) u16 kS[64 * 128];   // [key][d], slot = key*16 + (seg^(key&15))
  __shared__ alignas(16) u16 vS[128 * 64];   // [d][key], slot = d*8 + (kseg^(d&7))
  __shared__ alignas(16) u16 pS[4][32][72];  // per-wave P [q][key], +8 pad
  const int tid = threadIdx.x;
  const int lane = tid & 63;
  const int w = tid >> 6;
  const int ml = lane & 15, qd = lane >> 4;
  const int gx = blockIdx.x;
  const int half = gx >> 8, rem = gx & 255;
  const int bh = rem >> 3, q3 = rem & 7;
  const int qt = half ? q3 : (15 - q3);  // pair long+short tiles across halves
  const int b = bh >> 4, h = bh & 15;
  const int hc = h * 128;
  const int m0 = qt * 128;
  const size_t rb = (size_t)(b * T_);
  // Q B-frags in registers for whole block: qf[qtile][k4]; lane n=ml -> q-row
  short8 qf[2][4];
#pragma unroll
  for (int m = 0; m < 2; ++m) {
    const u16* qp = qkv + (rb + m0 + w * 32 + m * 16 + ml) * LDQKV + hc;
#pragma unroll
    for (int k4 = 0; k4 < 4; ++k4) qf[m][k4] = *(const short8*)(qp + k4 * 32 + qd * 8);
  }
  float4v acc[2][8] = {};
  float mi[2] = {-1.0e30f, -1.0e30f}, li[2] = {0.f, 0.f};
  const int nchunk = 2 * qt + 2;
  // staging decode (closed forms)
  const int krow0 = w * 16 + qd;                    // + i*4
  const int vd0 = w * 32 + (lane >> 3);             // + i*8
  const int vsegoff = ((lane & 7) ^ (lane >> 3)) * 8;
  const size_t vtbase = ((size_t)bh * 128) * 2048;

  for (int c = 0; c < nchunk; ++c) {
    __syncthreads();
#pragma unroll
    for (int i = 0; i < 4; ++i) {
      int key = krow0 + i * 4;
      int seg = (ml ^ (i * 4 + qd)) * 8;
      async16(kS + (w * 4 + i) * 512,
              qkv + (rb + c * 64 + key) * LDQKV + C_ + hc + seg);
    }
#pragma unroll
    for (int i = 0; i < 4; ++i) {
      int d = vd0 + i * 8;
      async16(vS + (w * 4 + i) * 512,
              Vt + vtbase + (size_t)d * 2048 + c * 64 + vsegoff);
    }
    __syncthreads();
    if (c * 64 > m0 + w * 32 + 31) continue;  // all keys future for this wave
    // ---- S^T = K Q^T : s[kt][qtile], C-layout row=key(qd*4+r), col=q(ml) ----
    float4v s[4][2] = {};
#pragma unroll
    for (int kt = 0; kt < 4; ++kt) {
#pragma unroll
      for (int k4 = 0; k4 < 4; ++k4) {
        int key = kt * 16 + ml;
        int slot = key * 16 + ((k4 * 4 + qd) ^ key);  // key&15 == key-in-tile pattern
        short8 kf = *(const short8*)(kS + ((kt * 16 + ml) * 16 + ((k4 * 4 + qd) ^ ml)) * 8);
        (void)key; (void)slot;
        s[kt][0] = mfma_bf16(kf, qf[0][k4], s[kt][0]);
        s[kt][1] = mfma_bf16(kf, qf[1][k4], s[kt][1]);
      }
    }
    const bool domask = (c * 64 + 63) > (m0 + w * 32);
    float alpha[2];
#pragma unroll
    for (int m = 0; m < 2; ++m) {
      int qrow = m0 + w * 32 + m * 16 + ml;
      if (domask) {
#pragma unroll
        for (int kt = 0; kt < 4; ++kt)
#pragma unroll
          for (int r = 0; r < 4; ++r) {
            int key = c * 64 + kt * 16 + qd * 4 + r;
            if (key > qrow) s[kt][m][r] = -1.0e30f;
          }
      }
      float mx = -1.0e30f;
#pragma unroll
      for (int kt = 0; kt < 4; ++kt)
#pragma unroll
        for (int r = 0; r < 4; ++r) mx = fmaxf(mx, s[kt][m][r]);
      mx = fmaxf(mx, __shfl_xor(mx, 16, 64));
      mx = fmaxf(mx, __shfl_xor(mx, 32, 64));
      float mnew = fmaxf(mi[m], mx);
      float a = __expf(mi[m] - mnew);
      float sm = 0.f;
#pragma unroll
      for (int kt = 0; kt < 4; ++kt)
#pragma unroll
        for (int r = 0; r < 4; ++r) {
          float p = __expf(s[kt][m][r] - mnew);
          s[kt][m][r] = p;
          sm += p;
        }
      sm += __shfl_xor(sm, 16, 64);
      sm += __shfl_xor(sm, 32, 64);
      li[m] = li[m] * a + sm;
      mi[m] = mnew;
      alpha[m] = a;
      // P rows: 4 consecutive keys per reg-group -> b64 writes
#pragma unroll
      for (int kt = 0; kt < 4; ++kt) {
        uint2 pk;
        pk.x = pack2bf(s[kt][m][0], s[kt][m][1]);
        pk.y = pack2bf(s[kt][m][2], s[kt][m][3]);
        *(uint2*)&pS[w][m * 16 + ml][kt * 16 + qd * 4] = pk;
      }
    }
    // rescale O (alpha lives at lane ml=q'; broadcast to rows qd*4+r)
#pragma unroll
    for (int m = 0; m < 2; ++m) {
#pragma unroll
      for (int r = 0; r < 4; ++r) {
        float aq = __shfl(alpha[m], qd * 4 + r, 64);
#pragma unroll
        for (int dt = 0; dt < 8; ++dt) acc[m][dt][r] *= aq;
      }
    }
    // ---- O += P V ----
#pragma unroll
    for (int k2 = 0; k2 < 2; ++k2) {
      short8 pa0 = *(const short8*)&pS[w][ml][k2 * 32 + qd * 8];
      short8 pa1 = *(const short8*)&pS[w][16 + ml][k2 * 32 + qd * 8];
#pragma unroll
      for (int dt = 0; dt < 8; ++dt) {
        int d = dt * 16 + ml;
        short8 vf = *(const short8*)(vS + (d * 8 + ((k2 * 4 + qd) ^ (ml & 7))) * 8);
        acc[0][dt] = mfma_bf16(pa0, vf, acc[0][dt]);
        acc[1][dt] = mfma_bf16(pa1, vf, acc[1][dt]);
      }
    }
  }
  // ---- epilogue: O/l -> Q cols of qkv ----
#pragma unroll
  for (int m = 0; m < 2; ++m) {
#pragma unroll
    for (int r = 0; r < 4; ++r) {
      float inv = 1.0f / __shfl(li[m], qd * 4 + r, 64);
      size_t row = rb + m0 + w * 32 + m * 16 + qd * 4 + r;
#pragma unroll
      for (int dt = 0; dt < 8; ++dt)
        qkv[row * LDQKV + hc + dt * 16 + ml] = f2bf(acc[m][dt][r] * inv);
    }
  }
#endif
}

// Old flash attention (fallback path; expects unscaled Q).
__global__ __launch_bounds__(256, 2) void attn_fwd(u16* __restrict__ qkv) {
#if defined(__HIP_DEVICE_COMPILE__)
  __shared__ alignas(16) u16 ks[64][136];
  __shared__ alignas(16) u16 vt[128][72];
  __shared__ alignas(16) u16 pb[4][32][72];
  const int tid = threadIdx.x;
  const int lane = tid & 63;
  const int w = tid >> 6;
  const int ml = lane & 15, qd = lane >> 4;
  const int gx = blockIdx.x;
  const int half = gx >> 8;
  const int rem = gx & 255;
  const int bh = rem >> 3;
  const int q3 = rem & 7;
  const int qt = half ? q3 : (15 - q3);
  const int b = bh >> 4, h = bh & 15;
  const int hc = h * 128;
  const int m0 = qt * 128;
  const size_t rb = (size_t)(b * T_);
  short8 qf[2][4];
#pragma unroll
  for (int m = 0; m < 2; ++m) {
    const u16* qp = qkv + (rb + m0 + w * 32 + m * 16 + ml) * LDQKV + hc;
#pragma unroll
    for (int k4 = 0; k4 < 4; ++k4) qf[m][k4] = *(const short8*)(qp + k4 * 32 + qd * 8);
  }
  float4v acc[2][8] = {};
  float mi[2][4], li[2][4];
#pragma unroll
  for (int m = 0; m < 2; ++m)
#pragma unroll
    for (int r = 0; r < 4; ++r) { mi[m][r] = -1.0e30f; li[m][r] = 0.f; }
  const float scale = 0.08838834764831845f;
  const int srow = tid >> 2;
  const int scol = (tid & 3) * 32;
  const int nchunk = 2 * qt + 2;
  for (int c = 0; c < nchunk; ++c) {
    __syncthreads();
    {
      const u16* kp = qkv + (rb + c * 64 + srow) * LDQKV + C_ + hc + scol;
      const u16* vp = qkv + (rb + c * 64 + srow) * LDQKV + 2 * C_ + hc + scol;
#pragma unroll
      for (int i = 0; i < 4; ++i)
        *(uint4*)&ks[srow][scol + i * 8] = *(const uint4*)(kp + i * 8);
#pragma unroll
      for (int i = 0; i < 4; ++i) {
        uint4 vv = *(const uint4*)(vp + i * 8);
        const u16* e = (const u16*)&vv;
#pragma unroll
        for (int t = 0; t < 8; ++t) vt[scol + i * 8 + t][srow] = e[t];
      }
    }
    __syncthreads();
    if (c * 64 > m0 + w * 32 + 31) continue;
    float4v s[2][4] = {};
#pragma unroll
    for (int t = 0; t < 4; ++t) {
#pragma unroll
      for (int k4 = 0; k4 < 4; ++k4) {
        short8 bf = *(const short8*)(&ks[t * 16 + ml][k4 * 32 + qd * 8]);
        s[0][t] = mfma_bf16(qf[0][k4], bf, s[0][t]);
        s[1][t] = mfma_bf16(qf[1][k4], bf, s[1][t]);
      }
    }
    const bool domask = (c * 64 + 63) > (m0 + w * 32);
#pragma unroll
    for (int m = 0; m < 2; ++m) {
      float al[4];
#pragma unroll
      for (int r = 0; r < 4; ++r) {
        float x0 = s[m][0][r] * scale;
        float x1 = s[m][1][r] * scale;
        float x2 = s[m][2][r] * scale;
        float x3 = s[m][3][r] * scale;
        if (domask) {
          int row = m0 + w * 32 + m * 16 + qd * 4 + r;
          int j0 = c * 64 + ml;
          if (j0 > row) x0 = -1.0e30f;
          if (j0 + 16 > row) x1 = -1.0e30f;
          if (j0 + 32 > row) x2 = -1.0e30f;
          if (j0 + 48 > row) x3 = -1.0e30f;
        }
        float mx = fmaxf(fmaxf(x0, x1), fmaxf(x2, x3));
        mx = fmaxf(mx, __shfl_xor(mx, 1));
        mx = fmaxf(mx, __shfl_xor(mx, 2));
        mx = fmaxf(mx, __shfl_xor(mx, 4));
        mx = fmaxf(mx, __shfl_xor(mx, 8));
        float mnew = fmaxf(mi[m][r], mx);
        float a = __expf(mi[m][r] - mnew);
        float p0 = __expf(x0 - mnew);
        float p1 = __expf(x1 - mnew);
        float p2 = __expf(x2 - mnew);
        float p3 = __expf(x3 - mnew);
        float sm = p0 + p1 + p2 + p3;
        sm += __shfl_xor(sm, 1);
        sm += __shfl_xor(sm, 2);
        sm += __shfl_xor(sm, 4);
        sm += __shfl_xor(sm, 8);
        li[m][r] = li[m][r] * a + sm;
        mi[m][r] = mnew;
        al[r] = a;
        int prow = m * 16 + qd * 4 + r;
        pb[w][prow][ml] = f2bf(p0);
        pb[w][prow][16 + ml] = f2bf(p1);
        pb[w][prow][32 + ml] = f2bf(p2);
        pb[w][prow][48 + ml] = f2bf(p3);
      }
#pragma unroll
      for (int d = 0; d < 8; ++d) {
        acc[m][d][0] *= al[0];
        acc[m][d][1] *= al[1];
        acc[m][d][2] *= al[2];
        acc[m][d][3] *= al[3];
      }
    }
#pragma unroll
    for (int k2 = 0; k2 < 2; ++k2) {
      short8 pa0 = *(const short8*)(&pb[w][ml][k2 * 32 + qd * 8]);
      short8 pa1 = *(const short8*)(&pb[w][16 + ml][k2 * 32 + qd * 8]);
#pragma unroll
      for (int d = 0; d < 8; ++d) {
        short8 vf = *(const short8*)(&vt[d * 16 + ml][k2 * 32 + qd * 8]);
        acc[0][d] = mfma_bf16(pa0, vf, acc[0][d]);
        acc[1][d] = mfma_bf16(pa1, vf, acc[1][d]);
      }
    }
  }
#pragma unroll
  for (int m = 0; m < 2; ++m) {
#pragma unroll
    for (int r = 0; r < 4; ++r) {
      float inv = 1.0f / li[m][r];
      size_t row = rb + m0 + w * 32 + m * 16 + qd * 4 + r;
#pragma unroll
      for (int d = 0; d < 8; ++d)
        qkv[row * LDQKV + hc + d * 16 + ml] = f2bf(acc[m][d][r] * inv);
    }
  }
#endif
}

extern "C" void kernel_launch(void* const* d_in, const int* in_sizes, int n_in,
                              void* d_out, int out_size, void* d_ws, size_t ws_size,
                              hipStream_t stream) {
  const float* x = (const float*)d_in[0];     // [B,T,C] fp32
  const float* wqkv = (const float*)d_in[1];  // [C,3C] fp32
  const float* wout = (const float*)d_in[2];  // [C,C] fp32
  float* out = (float*)d_out;                 // [B,T,C] fp32
  char* ws = (char*)d_ws;
  u16* qkv = (u16*)ws;  // [4096, 6144] bf16 = 48 MB; Q cols reused as Y

  const size_t MB = 1024 * 1024;
  if (ws_size >= 96 * MB) {
    u16* xb = (u16*)(ws + 48 * MB);     // [4096,2048] bf16, 16 MB
    u16* wqkvT = (u16*)(ws + 64 * MB);  // [6144,2048] bf16, 24 MB
    u16* Vt = (u16*)(ws + 64 * MB);     // [32,128,2048] bf16, 16 MB (reuses wqkvT after GEMM1)
    u16* woutT = (u16*)(ws + 88 * MB);  // [2048,2048] bf16, 8 MB
    cast_f32_bf16<<<dim3(8192), dim3(256), 0, stream>>>(x, xb);
    castT_f32_bf16<<<dim3(192, 64), dim3(256), 0, stream>>>(wqkv, wqkvT, 2048, 6144);
    castT_f32_bf16<<<dim3(64, 64), dim3(256), 0, stream>>>(wout, woutT, 2048, 2048);
    gemm_bt<false><<<dim3(48, 32), dim3(256), 0, stream>>>(
        xb, wqkvT, qkv, 2048, 2048, 2048, 6144);
    rope_inplace<<<dim3(16384), dim3(256), 0, stream>>>(qkv, 0.08838834764831845f);
    vT_build<<<dim3(32, 32, 2), dim3(256), 0, stream>>>(qkv, Vt);
    attn_fwd2<<<dim3(512), dim3(256), 0, stream>>>(qkv, Vt);
    gemm_bt<true><<<dim3(16, 32), dim3(256), 0, stream>>>(
        qkv, woutT, out, 2048, 6144, 2048, 2048);
  } else {
    gemm_mixed<true, true, false><<<dim3(96, 64), dim3(256), 0, stream>>>(
        x, wqkv, qkv, 4096, 6144, 2048, 2048, 6144, 6144);
    rope_inplace<<<dim3(16384), dim3(256), 0, stream>>>(qkv, 1.0f);
    attn_fwd<<<dim3(512), dim3(256), 0, stream>>>(qkv);
    gemm_mixed<false, true, true><<<dim3(32, 64), dim3(256), 0, stream>>>(
        qkv, wout, out, 4096, 2048, 2048, 6144, 2048, 2048);
  }
}